// Round 1
// baseline (95.687 us; speedup 1.0000x reference)
//
#include <hip/hip_runtime.h>

// Npool: soft max-pool along last axis.
// x: (8,32,64,4096) f32 -> out: (8,32,64,2047) f32
// window=4, stride=2, n_neighbor=1.
// Per window: mi = first-argmax. mi in {0,3} -> out = max.
//             mi in {1,2} -> out = 0.25*win[mi-1] + 0.5*win[mi] + 0.25*win[mi+1].

#define ROW_W 4096
#define OUT_W 2047

__global__ __launch_bounds__(256) void npool_kernel(const float* __restrict__ x,
                                                    float* __restrict__ out) {
    const int o = blockIdx.x * 256 + threadIdx.x;   // output position in row
    const int row = blockIdx.y;                     // flattened (B,C,H) row, 16384 rows
    if (o >= OUT_W) return;

    const float* rp = x + (size_t)row * ROW_W + 2 * o;
    const float2 a = *reinterpret_cast<const float2*>(rp);       // w0, w1
    const float2 b = *reinterpret_cast<const float2*>(rp + 2);   // w2, w3
    const float w0 = a.x, w1 = a.y, w2 = b.x, w3 = b.y;

    // first-occurrence argmax (strict > keeps the first max, matching jnp.argmax)
    int mi = 0;
    float m = w0;
    if (w1 > m) { m = w1; mi = 1; }
    if (w2 > m) { m = w2; mi = 2; }
    if (w3 > m) { m = w3; mi = 3; }

    float res;
    if (mi == 0 || mi == 3) {
        res = m;                       // eff = 0: weight 1 on the max itself
    } else {
        const float lo = (mi == 1) ? w0 : w1;
        const float hi = (mi == 1) ? w2 : w3;
        res = 0.25f * lo + 0.5f * m + 0.25f * hi;   // eff = 1 triangular weights
    }

    out[(size_t)row * OUT_W + o] = res;
}

extern "C" void kernel_launch(void* const* d_in, const int* in_sizes, int n_in,
                              void* d_out, int out_size, void* d_ws, size_t ws_size,
                              hipStream_t stream) {
    const float* x = (const float*)d_in[0];
    float* out = (float*)d_out;

    const int rows = in_sizes[0] / ROW_W;           // 8*32*64 = 16384
    dim3 grid((OUT_W + 255) / 256, rows);           // (8, 16384)
    npool_kernel<<<grid, 256, 0, stream>>>(x, out);
}

// Round 2
// 74.419 us; speedup vs baseline: 1.2858x; 1.2858x over previous
//
#include <hip/hip_runtime.h>

// Npool: soft max-pool along last axis.
// x: (8,32,64,4096) f32 -> out: (8,32,64,2047) f32
// window=4, stride=2, n_neighbor=1.
// Per window: mi = first-argmax. mi in {0,3} -> out = max (eff=0).
//             mi in {1,2} -> out = 0.25*win[mi-1] + 0.5*win[mi] + 0.25*win[mi+1].
//
// One block per row (16384 rows). 256 threads × 8 strided outputs each.
// All 16 float2 loads issued up front -> 128 B in flight per thread (MLP),
// loads stride-8B / stores stride-4B across lanes: fully coalesced.

#define ROW_W 4096
#define OUT_W 2047
#define PER_T 8   // outputs per thread: 8*256 = 2048 >= 2047

__global__ __launch_bounds__(256) void npool_kernel(const float* __restrict__ x,
                                                    float* __restrict__ out) {
    const int tid = threadIdx.x;
    const int row = blockIdx.x;
    const float* rx = x + (size_t)row * ROW_W;
    float*       ro = out + (size_t)row * OUT_W;

    float2 a[PER_T], b[PER_T];

    // Issue all loads first (independent -> maximal outstanding bytes).
    #pragma unroll
    for (int k = 0; k < PER_T; ++k) {
        int o = tid + 256 * k;
        int oc = (o < OUT_W) ? o : (OUT_W - 1);   // clamp: only tid==255,k==7
        a[k] = *reinterpret_cast<const float2*>(rx + 2 * oc);
        b[k] = *reinterpret_cast<const float2*>(rx + 2 * oc + 2);
    }

    float res[PER_T];
    #pragma unroll
    for (int k = 0; k < PER_T; ++k) {
        const float w0 = a[k].x, w1 = a[k].y, w2 = b[k].x, w3 = b[k].y;

        // first-occurrence argmax (strict > keeps first max, matches jnp.argmax)
        int mi = 0;
        float m = w0;
        if (w1 > m) { m = w1; mi = 1; }
        if (w2 > m) { m = w2; mi = 2; }
        if (w3 > m) { m = w3; mi = 3; }

        const float lo = (mi == 1) ? w0 : w1;
        const float hi = (mi == 1) ? w2 : w3;
        const float interior = 0.25f * lo + 0.5f * m + 0.25f * hi;
        res[k] = (mi == 0 || mi == 3) ? m : interior;
    }

    #pragma unroll
    for (int k = 0; k < PER_T; ++k) {
        int o = tid + 256 * k;
        if (k < PER_T - 1 || o < OUT_W) ro[o] = res[k];
    }
}

extern "C" void kernel_launch(void* const* d_in, const int* in_sizes, int n_in,
                              void* d_out, int out_size, void* d_ws, size_t ws_size,
                              hipStream_t stream) {
    const float* x = (const float*)d_in[0];
    float* out = (float*)d_out;

    const int rows = in_sizes[0] / ROW_W;   // 8*32*64 = 16384
    npool_kernel<<<rows, 256, 0, stream>>>(x, out);
}